// Round 2
// baseline (1928.887 us; speedup 1.0000x reference)
//
#include <hip/hip_runtime.h>

// Problem constants (match reference)
constexpr int kN = 100000;   // nodes
constexpr int kE = 400000;   // edges per relation
constexpr int kR = 4;        // relations
constexpr int kG = 64;       // graphs
constexpr int kIN = 64;      // input feature dim
constexpr int kH = 128;      // hidden dim
constexpr int kC = 2;        // classes

// scan config
constexpr int SCAN_TPB = 256;
constexpr int SCAN_CHUNK = 1024;                      // 4 elements per thread
constexpr int NBLK = (kN + SCAN_CHUNK - 1) / SCAN_CHUNK; // 98 blocks per relation

// ---------------- workspace layout ----------------
constexpr size_t SZ_H  = (size_t)kN * kH * 4;   // 51,200,000
constexpr size_t SZ_RN = (size_t)kR * kN * 4;   // 1,600,000
constexpr size_t SZ_RE = (size_t)kR * kE * 4;   // 6,400,000
constexpr size_t OFF_HA   = 0;
constexpr size_t OFF_HB   = OFF_HA + SZ_H;
constexpr size_t OFF_AGG  = OFF_HB + SZ_H;
constexpr size_t OFF_DEGO = OFF_AGG + SZ_H;      // int, zeroed each call
constexpr size_t OFF_DEGI = OFF_DEGO + SZ_RN;    // int, zeroed each call
constexpr size_t OFF_CUR  = OFF_DEGI + SZ_RN;    // int, zeroed each call
constexpr size_t OFF_PRE  = OFF_CUR + SZ_RN;     // int
constexpr size_t OFF_CSRS = OFF_PRE + SZ_RN;     // int  [R*E]
constexpr size_t OFF_CSRC = OFF_CSRS + SZ_RE;    // f32  [R*E]
constexpr size_t OFF_BSUM = OFF_CSRC + SZ_RE;    // int  [R*NBLK]
constexpr size_t OFF_POOL = OFF_BSUM + 4096;
constexpr size_t OFF_Z1   = OFF_POOL + (size_t)kG * kH * 4;
constexpr size_t OFF_Z2   = OFF_Z1 + (size_t)kG * kH * 4;

// ---------------- kernels ----------------

// 1) degree histogram per relation (deg_out from src, deg_in from dst)
__global__ void k_deg(const int* __restrict__ src, const int* __restrict__ dst,
                      int* __restrict__ deg_o, int* __restrict__ deg_i) {
    int i = blockIdx.x * blockDim.x + threadIdx.x;
    if (i >= kR * kE) return;
    int r = i / kE;
    atomicAdd(&deg_o[r * kN + src[i]], 1);
    atomicAdd(&deg_i[r * kN + dst[i]], 1);
}

// 2) block-wise exclusive scan of deg_in -> prefix (relation-relative), block sums out
__global__ void k_scan1(const int* __restrict__ counts, int* __restrict__ prefix,
                        int* __restrict__ bsums) {
    __shared__ int lds[SCAN_TPB];
    int r = blockIdx.x / NBLK;
    int b = blockIdx.x % NBLK;
    int base = b * SCAN_CHUNK;
    int t = threadIdx.x;
    int v[4]; int s = 0;
    #pragma unroll
    for (int k = 0; k < 4; k++) {
        int idx = base + t * 4 + k;
        v[k] = (idx < kN) ? counts[r * kN + idx] : 0;
        s += v[k];
    }
    lds[t] = s; __syncthreads();
    for (int off = 1; off < SCAN_TPB; off <<= 1) {
        int x = (t >= off) ? lds[t - off] : 0;
        __syncthreads();
        lds[t] += x;
        __syncthreads();
    }
    int ex = (t > 0) ? lds[t - 1] : 0;
    int run = ex;
    #pragma unroll
    for (int k = 0; k < 4; k++) {
        int idx = base + t * 4 + k;
        if (idx < kN) prefix[r * kN + idx] = run;
        run += v[k];
    }
    if (t == 0) bsums[blockIdx.x] = lds[SCAN_TPB - 1];
}

// 3) scan the per-block sums (per relation), in-place -> exclusive block offsets
__global__ void k_scan2(int* __restrict__ bsums) {
    __shared__ int lds[128];
    int t = threadIdx.x; // 128 threads
    for (int r = 0; r < kR; r++) {
        int v = (t < NBLK) ? bsums[r * NBLK + t] : 0;
        lds[t] = v; __syncthreads();
        for (int off = 1; off < 128; off <<= 1) {
            int x = (t >= off) ? lds[t - off] : 0;
            __syncthreads();
            lds[t] += x;
            __syncthreads();
        }
        int ex = (t > 0) ? lds[t - 1] : 0;
        if (t < NBLK) bsums[r * NBLK + t] = ex;
        __syncthreads();
    }
}

// 4) add block offsets to element prefixes
__global__ void k_scan3(int* __restrict__ prefix, const int* __restrict__ bsums) {
    int r = blockIdx.x / NBLK;
    int b = blockIdx.x % NBLK;
    int off = bsums[blockIdx.x];
    int base = b * SCAN_CHUNK + threadIdx.x;
    #pragma unroll
    for (int k = 0; k < 4; k++) {
        int idx = base + k * SCAN_TPB;
        if (idx < kN) prefix[r * kN + idx] += off;
    }
}

// 5) fill CSR: slot position claimed by atomic cursor; store src idx + edge coefficient
__global__ void k_fill(const int* __restrict__ src, const int* __restrict__ dst,
                       const int* __restrict__ deg_o, const int* __restrict__ deg_i,
                       const int* __restrict__ prefix, int* __restrict__ cursor,
                       int* __restrict__ csr_src, float* __restrict__ csr_coef) {
    int i = blockIdx.x * blockDim.x + threadIdx.x;
    if (i >= kR * kE) return;
    int r = i / kE;
    int s = src[i], d = dst[i];
    int pos = prefix[r * kN + d] + atomicAdd(&cursor[r * kN + d], 1);
    float co = rsqrtf((float)max(deg_o[r * kN + s], 1)) *
               rsqrtf((float)max(deg_i[r * kN + d], 1));
    csr_src[r * kE + pos] = s;
    csr_coef[r * kE + pos] = co;
}

// 6) input linear + ReLU: h = relu(x @ W_in + b_in), x [N,64], W [64,128]
__global__ __launch_bounds__(256) void k_inlin(const float* __restrict__ x,
                                               const float* __restrict__ W,
                                               const float* __restrict__ b,
                                               float* __restrict__ h) {
    __shared__ float Ws[64][128];
    __shared__ float xs[64][64];
    int t = threadIdx.x;
    int n0 = blockIdx.x * 64;
    for (int i = t; i < 64 * 128; i += 256) Ws[i >> 7][i & 127] = W[i];
    for (int i = t; i < 64 * 64; i += 256) {
        int rr = i >> 6, cc = i & 63;
        int n = n0 + rr;
        xs[rr][cc] = (n < kN) ? x[(size_t)n * kIN + cc] : 0.f;
    }
    __syncthreads();
    int jg = t & 31, j0 = jg * 4, rg = t >> 5; // rg in 0..7, 8 rows each
    float acc[8][4] = {};
    for (int k = 0; k < 64; k++) {
        float4 wv = *(const float4*)&Ws[k][j0];
        #pragma unroll
        for (int i = 0; i < 8; i++) {
            float av = xs[rg * 8 + i][k];
            acc[i][0] += av * wv.x; acc[i][1] += av * wv.y;
            acc[i][2] += av * wv.z; acc[i][3] += av * wv.w;
        }
    }
    #pragma unroll
    for (int i = 0; i < 8; i++) {
        int n = n0 + rg * 8 + i;
        if (n < kN) {
            float4 res;
            res.x = fmaxf(acc[i][0] + b[j0 + 0], 0.f);
            res.y = fmaxf(acc[i][1] + b[j0 + 1], 0.f);
            res.z = fmaxf(acc[i][2] + b[j0 + 2], 0.f);
            res.w = fmaxf(acc[i][3] + b[j0 + 3], 0.f);
            *(float4*)&h[(size_t)n * kH + j0] = res;
        }
    }
}

// 7) gather-aggregate one relation: agg[n] = sum_{e: dst=n} coef_e * h[src_e]
//    one wave (64 lanes) per node, 2 features per lane
__global__ __launch_bounds__(256) void k_agg(const float* __restrict__ hin,
                                             const int* __restrict__ csr_src,
                                             const float* __restrict__ csr_coef,
                                             const int* __restrict__ prefix,
                                             const int* __restrict__ cnt,
                                             float* __restrict__ agg, int r) {
    int wave = threadIdx.x >> 6, lane = threadIdx.x & 63;
    int n = blockIdx.x * 4 + wave;
    if (n >= kN) return;
    int beg = prefix[r * kN + n];
    int c = cnt[r * kN + n];
    const int* sp = csr_src + (size_t)r * kE + beg;
    const float* cp = csr_coef + (size_t)r * kE + beg;
    float a0 = 0.f, a1 = 0.f;
    for (int e = 0; e < c; e++) {
        int s = sp[e];
        float co = cp[e];
        const float* hrow = hin + (size_t)s * kH;
        a0 += co * hrow[lane];
        a1 += co * hrow[64 + lane];
    }
    agg[(size_t)n * kH + lane] = a0;
    agg[(size_t)n * kH + 64 + lane] = a1;
}

// 8) matmul-accumulate: out[n,:] (+)= agg[n,:] @ W (128x128); init with summed
//    relation bias on first relation; optional ReLU on last relation.
__global__ __launch_bounds__(256) void k_mm(const float* __restrict__ A,
                                            const float* __restrict__ W,
                                            const float* __restrict__ brel,
                                            float* __restrict__ out,
                                            int doInit, int doRelu) {
    __shared__ float Ws[64][128];
    __shared__ float As[32][128];
    int t = threadIdx.x;
    int n0 = blockIdx.x * 32; // N divisible by 32
    for (int i = t; i < 32 * 128; i += 256) {
        int rr = i >> 7, cc = i & 127;
        As[rr][cc] = A[(size_t)(n0 + rr) * kH + cc];
    }
    int jg = t & 31, j0 = jg * 4, rg = t >> 5; // 8 row-groups of 4 rows
    float acc[4][4] = {};
    for (int ph = 0; ph < 2; ph++) {
        __syncthreads();
        for (int i = t; i < 64 * 128; i += 256) {
            int rr = i >> 7, cc = i & 127;
            Ws[rr][cc] = W[(size_t)(ph * 64 + rr) * kH + cc];
        }
        __syncthreads();
        int kbase = ph * 64;
        for (int k = 0; k < 64; k++) {
            float4 wv = *(const float4*)&Ws[k][j0];
            #pragma unroll
            for (int i = 0; i < 4; i++) {
                float av = As[rg * 4 + i][kbase + k];
                acc[i][0] += av * wv.x; acc[i][1] += av * wv.y;
                acc[i][2] += av * wv.z; acc[i][3] += av * wv.w;
            }
        }
    }
    float4 bias;
    if (doInit) {
        bias.x = brel[0 * kH + j0 + 0] + brel[1 * kH + j0 + 0] + brel[2 * kH + j0 + 0] + brel[3 * kH + j0 + 0];
        bias.y = brel[0 * kH + j0 + 1] + brel[1 * kH + j0 + 1] + brel[2 * kH + j0 + 1] + brel[3 * kH + j0 + 1];
        bias.z = brel[0 * kH + j0 + 2] + brel[1 * kH + j0 + 2] + brel[2 * kH + j0 + 2] + brel[3 * kH + j0 + 2];
        bias.w = brel[0 * kH + j0 + 3] + brel[1 * kH + j0 + 3] + brel[2 * kH + j0 + 3] + brel[3 * kH + j0 + 3];
    }
    #pragma unroll
    for (int i = 0; i < 4; i++) {
        int n = n0 + rg * 4 + i;
        float* op = out + (size_t)n * kH + j0;
        float4 base;
        if (doInit) base = bias;
        else base = *(const float4*)op;
        float4 res;
        res.x = base.x + acc[i][0]; res.y = base.y + acc[i][1];
        res.z = base.z + acc[i][2]; res.w = base.w + acc[i][3];
        if (doRelu) {
            res.x = fmaxf(res.x, 0.f); res.y = fmaxf(res.y, 0.f);
            res.z = fmaxf(res.z, 0.f); res.w = fmaxf(res.w, 0.f);
        }
        *(float4*)op = res;
    }
}

// 9) per-graph mean pool (graph_ids sorted): one block per graph
__global__ void k_pool(const float* __restrict__ h, const int* __restrict__ gid,
                       float* __restrict__ pooled) {
    int g = blockIdx.x, j = threadIdx.x; // 128 threads
    int lo = 0, hi = kN;
    while (lo < hi) { int mid = (lo + hi) >> 1; if (gid[mid] < g) lo = mid + 1; else hi = mid; }
    int start = lo;
    int lo2 = lo; hi = kN;
    while (lo2 < hi) { int mid = (lo2 + hi) >> 1; if (gid[mid] <= g) lo2 = mid + 1; else hi = mid; }
    int end = lo2;
    float s = 0.f;
    for (int n = start; n < end; n++) s += h[(size_t)n * kH + j];
    int cnt = end - start;
    pooled[g * kH + j] = s / (float)max(cnt, 1);
}

// 10) MLP head layer: out = (relu?)(in @ W + b), in [G,128], W [128,128]
__global__ void k_head(const float* __restrict__ in, const float* __restrict__ W,
                       const float* __restrict__ b, float* __restrict__ outv, int doRelu) {
    __shared__ float ps[128];
    int g = blockIdx.x, j = threadIdx.x;
    ps[j] = in[g * kH + j];
    __syncthreads();
    float acc = b[j];
    for (int k = 0; k < kH; k++) acc += ps[k] * W[k * kH + j];
    outv[g * kH + j] = doRelu ? fmaxf(acc, 0.f) : acc;
}

// 11) final head: [G,128] @ [128,2] + b
__global__ void k_head3(const float* __restrict__ z, const float* __restrict__ W,
                        const float* __restrict__ b, float* __restrict__ outv) {
    int t = threadIdx.x; // 128 = 64 graphs * 2 classes
    int g = t >> 1, c = t & 1;
    float acc = b[c];
    for (int k = 0; k < kH; k++) acc += z[g * kH + k] * W[k * kC + c];
    outv[g * kC + c] = acc;
}

// ---------------- launch ----------------
extern "C" void kernel_launch(void* const* d_in, const int* in_sizes, int n_in,
                              void* d_out, int out_size, void* d_ws, size_t ws_size,
                              hipStream_t stream) {
    (void)in_sizes; (void)n_in; (void)out_size; (void)ws_size;
    const float* x    = (const float*)d_in[0];
    const int*   src  = (const int*)d_in[1];
    const int*   dst  = (const int*)d_in[2];
    const int*   gid  = (const int*)d_in[3];
    const float* W_in = (const float*)d_in[4];
    const float* b_in = (const float*)d_in[5];
    const float* W1   = (const float*)d_in[6];
    const float* b1   = (const float*)d_in[7];
    const float* W2   = (const float*)d_in[8];
    const float* b2   = (const float*)d_in[9];
    const float* Wm1  = (const float*)d_in[10];
    const float* bm1  = (const float*)d_in[11];
    const float* Wm2  = (const float*)d_in[12];
    const float* bm2  = (const float*)d_in[13];
    const float* Wm3  = (const float*)d_in[14];
    const float* bm3  = (const float*)d_in[15];
    float* out = (float*)d_out;

    char* ws = (char*)d_ws;
    float* h_a     = (float*)(ws + OFF_HA);
    float* h_b     = (float*)(ws + OFF_HB);
    float* agg     = (float*)(ws + OFF_AGG);
    int*   deg_o   = (int*)(ws + OFF_DEGO);
    int*   deg_i   = (int*)(ws + OFF_DEGI);
    int*   cursor  = (int*)(ws + OFF_CUR);
    int*   prefix  = (int*)(ws + OFF_PRE);
    int*   csr_src = (int*)(ws + OFF_CSRS);
    float* csr_cof = (float*)(ws + OFF_CSRC);
    int*   bsums   = (int*)(ws + OFF_BSUM);
    float* pooled  = (float*)(ws + OFF_POOL);
    float* z1      = (float*)(ws + OFF_Z1);
    float* z2      = (float*)(ws + OFF_Z2);

    // zero the three atomic-counter arrays (contiguous)
    hipMemsetAsync(ws + OFF_DEGO, 0, 3 * SZ_RN, stream);

    int egrid = (kR * kE + 255) / 256;
    k_deg<<<egrid, 256, 0, stream>>>(src, dst, deg_o, deg_i);
    k_scan1<<<kR * NBLK, SCAN_TPB, 0, stream>>>(deg_i, prefix, bsums);
    k_scan2<<<1, 128, 0, stream>>>(bsums);
    k_scan3<<<kR * NBLK, SCAN_TPB, 0, stream>>>(prefix, bsums);
    k_fill<<<egrid, 256, 0, stream>>>(src, dst, deg_o, deg_i, prefix, cursor, csr_src, csr_cof);

    k_inlin<<<(kN + 63) / 64, 256, 0, stream>>>(x, W_in, b_in, h_a);

    // layer 1: h_b = relu(sum_r A_r h_a W1_r + sum_r b1_r)
    for (int r = 0; r < kR; r++) {
        k_agg<<<(kN + 3) / 4, 256, 0, stream>>>(h_a, csr_src, csr_cof, prefix, deg_i, agg, r);
        k_mm<<<kN / 32, 256, 0, stream>>>(agg, W1 + (size_t)r * kH * kH, b1, h_b,
                                          r == 0 ? 1 : 0, r == kR - 1 ? 1 : 0);
    }
    // layer 2: h_a = sum_r A_r h_b W2_r + sum_r b2_r   (no relu)
    for (int r = 0; r < kR; r++) {
        k_agg<<<(kN + 3) / 4, 256, 0, stream>>>(h_b, csr_src, csr_cof, prefix, deg_i, agg, r);
        k_mm<<<kN / 32, 256, 0, stream>>>(agg, W2 + (size_t)r * kH * kH, b2, h_a,
                                          r == 0 ? 1 : 0, 0);
    }

    k_pool<<<kG, 128, 0, stream>>>(h_a, gid, pooled);
    k_head<<<kG, 128, 0, stream>>>(pooled, Wm1, bm1, z1, 1);
    k_head<<<kG, 128, 0, stream>>>(z1, Wm2, bm2, z2, 1);
    k_head3<<<1, 128, 0, stream>>>(z2, Wm3, bm3, out);
}

// Round 3
// 1524.221 us; speedup vs baseline: 1.2655x; 1.2655x over previous
//
#include <hip/hip_runtime.h>

// Problem constants (match reference)
constexpr int kN = 100000;   // nodes
constexpr int kE = 400000;   // edges per relation
constexpr int kR = 4;        // relations
constexpr int kG = 64;       // graphs
constexpr int kIN = 64;      // input feature dim
constexpr int kH = 128;      // hidden dim
constexpr int kC = 2;        // classes

// scan config
constexpr int SCAN_TPB = 256;
constexpr int SCAN_CHUNK = 1024;                      // 4 elements per thread
constexpr int NBLK = (kN + SCAN_CHUNK - 1) / SCAN_CHUNK; // 98 blocks per relation

// ---------------- workspace layout ----------------
constexpr size_t SZ_H  = (size_t)kN * kH * 4;   // 51,200,000
constexpr size_t SZ_RN = (size_t)kR * kN * 4;   // 1,600,000
constexpr size_t SZ_RE = (size_t)kR * kE * 4;   // 6,400,000
constexpr size_t OFF_HA   = 0;
constexpr size_t OFF_HB   = OFF_HA + SZ_H;
constexpr size_t OFF_DEGO = OFF_HB + SZ_H;       // int, zeroed each call
constexpr size_t OFF_DEGI = OFF_DEGO + SZ_RN;    // int, zeroed each call
constexpr size_t OFF_CUR  = OFF_DEGI + SZ_RN;    // int, zeroed each call
constexpr size_t OFF_PRE  = OFF_CUR + SZ_RN;     // int
constexpr size_t OFF_CSRS = OFF_PRE + SZ_RN;     // int  [R*E]
constexpr size_t OFF_CSRC = OFF_CSRS + SZ_RE;    // f32  [R*E]
constexpr size_t OFF_BSUM = OFF_CSRC + SZ_RE;    // int  [R*NBLK]
constexpr size_t OFF_POOL = OFF_BSUM + 4096;     // f32 [G,H], zeroed each call
constexpr size_t OFF_Z1   = OFF_POOL + (size_t)kG * kH * 4;
constexpr size_t OFF_Z2   = OFF_Z1 + (size_t)kG * kH * 4;

// ---------------- CSR build ----------------

__global__ void k_deg(const int* __restrict__ src, const int* __restrict__ dst,
                      int* __restrict__ deg_o, int* __restrict__ deg_i) {
    int i = blockIdx.x * blockDim.x + threadIdx.x;
    if (i >= kR * kE) return;
    int r = i / kE;
    atomicAdd(&deg_o[r * kN + src[i]], 1);
    atomicAdd(&deg_i[r * kN + dst[i]], 1);
}

__global__ void k_scan1(const int* __restrict__ counts, int* __restrict__ prefix,
                        int* __restrict__ bsums) {
    __shared__ int lds[SCAN_TPB];
    int r = blockIdx.x / NBLK;
    int b = blockIdx.x % NBLK;
    int base = b * SCAN_CHUNK;
    int t = threadIdx.x;
    int v[4]; int s = 0;
    #pragma unroll
    for (int k = 0; k < 4; k++) {
        int idx = base + t * 4 + k;
        v[k] = (idx < kN) ? counts[r * kN + idx] : 0;
        s += v[k];
    }
    lds[t] = s; __syncthreads();
    for (int off = 1; off < SCAN_TPB; off <<= 1) {
        int x = (t >= off) ? lds[t - off] : 0;
        __syncthreads();
        lds[t] += x;
        __syncthreads();
    }
    int ex = (t > 0) ? lds[t - 1] : 0;
    int run = ex;
    #pragma unroll
    for (int k = 0; k < 4; k++) {
        int idx = base + t * 4 + k;
        if (idx < kN) prefix[r * kN + idx] = run;
        run += v[k];
    }
    if (t == 0) bsums[blockIdx.x] = lds[SCAN_TPB - 1];
}

__global__ void k_scan2(int* __restrict__ bsums) {
    __shared__ int lds[128];
    int t = threadIdx.x; // 128 threads
    for (int r = 0; r < kR; r++) {
        int v = (t < NBLK) ? bsums[r * NBLK + t] : 0;
        lds[t] = v; __syncthreads();
        for (int off = 1; off < 128; off <<= 1) {
            int x = (t >= off) ? lds[t - off] : 0;
            __syncthreads();
            lds[t] += x;
            __syncthreads();
        }
        int ex = (t > 0) ? lds[t - 1] : 0;
        if (t < NBLK) bsums[r * NBLK + t] = ex;
        __syncthreads();
    }
}

__global__ void k_scan3(int* __restrict__ prefix, const int* __restrict__ bsums) {
    int r = blockIdx.x / NBLK;
    int b = blockIdx.x % NBLK;
    int off = bsums[blockIdx.x];
    int base = b * SCAN_CHUNK + threadIdx.x;
    #pragma unroll
    for (int k = 0; k < 4; k++) {
        int idx = base + k * SCAN_TPB;
        if (idx < kN) prefix[r * kN + idx] += off;
    }
    (void)r;
}

__global__ void k_fill(const int* __restrict__ src, const int* __restrict__ dst,
                       const int* __restrict__ deg_o, const int* __restrict__ deg_i,
                       const int* __restrict__ prefix, int* __restrict__ cursor,
                       int* __restrict__ csr_src, float* __restrict__ csr_coef) {
    int i = blockIdx.x * blockDim.x + threadIdx.x;
    if (i >= kR * kE) return;
    int r = i / kE;
    int s = src[i], d = dst[i];
    int pos = prefix[r * kN + d] + atomicAdd(&cursor[r * kN + d], 1);
    float co = rsqrtf((float)max(deg_o[r * kN + s], 1)) *
               rsqrtf((float)max(deg_i[r * kN + d], 1));
    csr_src[r * kE + pos] = s;
    csr_coef[r * kE + pos] = co;
}

// ---------------- input linear ----------------
__global__ __launch_bounds__(256) void k_inlin(const float* __restrict__ x,
                                               const float* __restrict__ W,
                                               const float* __restrict__ b,
                                               float* __restrict__ h) {
    __shared__ float Ws[64][128];
    __shared__ float xs[64][64];
    int t = threadIdx.x;
    int n0 = blockIdx.x * 64;
    for (int i = t; i < 64 * 128; i += 256) Ws[i >> 7][i & 127] = W[i];
    for (int i = t; i < 64 * 64; i += 256) {
        int rr = i >> 6, cc = i & 63;
        int n = n0 + rr;
        xs[rr][cc] = (n < kN) ? x[(size_t)n * kIN + cc] : 0.f;
    }
    __syncthreads();
    int jg = t & 31, j0 = jg * 4, rg = t >> 5; // rg in 0..7, 8 rows each
    float acc[8][4] = {};
    for (int k = 0; k < 64; k++) {
        float4 wv = *(const float4*)&Ws[k][j0];
        #pragma unroll
        for (int i = 0; i < 8; i++) {
            float av = xs[rg * 8 + i][k];
            acc[i][0] += av * wv.x; acc[i][1] += av * wv.y;
            acc[i][2] += av * wv.z; acc[i][3] += av * wv.w;
        }
    }
    #pragma unroll
    for (int i = 0; i < 8; i++) {
        int n = n0 + rg * 8 + i;
        if (n < kN) {
            float4 res;
            res.x = fmaxf(acc[i][0] + b[j0 + 0], 0.f);
            res.y = fmaxf(acc[i][1] + b[j0 + 1], 0.f);
            res.z = fmaxf(acc[i][2] + b[j0 + 2], 0.f);
            res.w = fmaxf(acc[i][3] + b[j0 + 3], 0.f);
            *(float4*)&h[(size_t)n * kH + j0] = res;
        }
    }
}

// ---------------- fused RGCN layer ----------------
// out[n,:] = (relu?)( sum_r (A_r hin)[n,:] @ W_r + sum_r b_r )
// One block = 32 nodes. Per relation: gather-aggregate into LDS As, then
// FMA against W_r streamed through LDS in two 64-row chunks. All 4 relations
// accumulate in registers; out written exactly once (no agg buffer, no RMW).
__global__ __launch_bounds__(256) void k_layer(
    const float* __restrict__ hin, const int* __restrict__ csr_src,
    const float* __restrict__ csr_coef, const int* __restrict__ prefix,
    const int* __restrict__ cnt, const float* __restrict__ W,
    const float* __restrict__ brel, float* __restrict__ out, int doRelu) {
    __shared__ float As[32][128];
    __shared__ float Ws[64][128];
    int t = threadIdx.x, wave = t >> 6, lane = t & 63;
    int n0 = blockIdx.x * 32;                 // kN % 32 == 0
    int jg = t & 31, j0 = jg * 4, rg = t >> 5;
    float acc[4][4] = {};
    for (int r = 0; r < kR; r++) {
        __syncthreads();                      // As free (prev relation's reads done)
        // gather phase: wave handles 8 nodes, 2 features per lane
        #pragma unroll
        for (int i = 0; i < 8; i++) {
            int n = n0 + wave * 8 + i;
            int beg = prefix[r * kN + n];
            int c = cnt[r * kN + n];
            const int* sp = csr_src + (size_t)r * kE + beg;
            const float* cp = csr_coef + (size_t)r * kE + beg;
            float a0 = 0.f, a1 = 0.f;
            for (int e = 0; e < c; e++) {
                int s = sp[e];
                float co = cp[e];
                const float* hr = hin + (size_t)s * kH;
                a0 += co * hr[lane];
                a1 += co * hr[64 + lane];
            }
            As[wave * 8 + i][lane] = a0;
            As[wave * 8 + i][64 + lane] = a1;
        }
        for (int ph = 0; ph < 2; ph++) {
            __syncthreads();                  // As ready / prev Ws consumed
            for (int i = t; i < 64 * 128; i += 256) {
                int rr = i >> 7, cc = i & 127;
                Ws[rr][cc] = W[((size_t)r * kH + ph * 64 + rr) * kH + cc];
            }
            __syncthreads();
            int kb = ph * 64;
            for (int k = 0; k < 64; k++) {
                float4 wv = *(const float4*)&Ws[k][j0];
                #pragma unroll
                for (int i = 0; i < 4; i++) {
                    float av = As[rg * 4 + i][kb + k];
                    acc[i][0] += av * wv.x; acc[i][1] += av * wv.y;
                    acc[i][2] += av * wv.z; acc[i][3] += av * wv.w;
                }
            }
        }
    }
    float4 bias;
    bias.x = brel[0 * kH + j0 + 0] + brel[1 * kH + j0 + 0] + brel[2 * kH + j0 + 0] + brel[3 * kH + j0 + 0];
    bias.y = brel[0 * kH + j0 + 1] + brel[1 * kH + j0 + 1] + brel[2 * kH + j0 + 1] + brel[3 * kH + j0 + 1];
    bias.z = brel[0 * kH + j0 + 2] + brel[1 * kH + j0 + 2] + brel[2 * kH + j0 + 2] + brel[3 * kH + j0 + 2];
    bias.w = brel[0 * kH + j0 + 3] + brel[1 * kH + j0 + 3] + brel[2 * kH + j0 + 3] + brel[3 * kH + j0 + 3];
    #pragma unroll
    for (int i = 0; i < 4; i++) {
        int n = n0 + rg * 4 + i;
        float4 res;
        res.x = bias.x + acc[i][0]; res.y = bias.y + acc[i][1];
        res.z = bias.z + acc[i][2]; res.w = bias.w + acc[i][3];
        if (doRelu) {
            res.x = fmaxf(res.x, 0.f); res.y = fmaxf(res.y, 0.f);
            res.z = fmaxf(res.z, 0.f); res.w = fmaxf(res.w, 0.f);
        }
        *(float4*)&out[(size_t)n * kH + j0] = res;
    }
}

// ---------------- pooling (2-stage) ----------------
// stage A: each block covers 128 contiguous nodes; graph_ids sorted so we
// run-length accumulate per feature and flush via f32 atomics on transitions.
__global__ void k_pool_acc(const float* __restrict__ h, const int* __restrict__ gid,
                           float* __restrict__ pooled) {
    int j = threadIdx.x;                 // 128 threads = feature
    int base = blockIdx.x * 128;
    if (base >= kN) return;
    int end = min(base + 128, kN);
    int curg = gid[base];
    float acc = 0.f;
    for (int n = base; n < end; n++) {
        int g = gid[n];                  // uniform -> scalar load
        if (g != curg) {
            atomicAdd(&pooled[curg * kH + j], acc);
            acc = 0.f; curg = g;
        }
        acc += h[(size_t)n * kH + j];
    }
    atomicAdd(&pooled[curg * kH + j], acc);
}

// stage B: divide by per-graph count (binary search on sorted gid)
__global__ void k_pool_fin(const int* __restrict__ gid, float* __restrict__ pooled) {
    int g = blockIdx.x, j = threadIdx.x; // 64 blocks x 128 threads
    int lo = 0, hi = kN;
    while (lo < hi) { int m = (lo + hi) >> 1; if (gid[m] < g) lo = m + 1; else hi = m; }
    int s = lo;
    lo = s; hi = kN;
    while (lo < hi) { int m = (lo + hi) >> 1; if (gid[m] <= g) lo = m + 1; else hi = m; }
    int c = lo - s;
    pooled[g * kH + j] /= (float)max(c, 1);
}

// ---------------- MLP head ----------------
__global__ void k_head(const float* __restrict__ in, const float* __restrict__ W,
                       const float* __restrict__ b, float* __restrict__ outv, int doRelu) {
    __shared__ float ps[128];
    int g = blockIdx.x, j = threadIdx.x;
    ps[j] = in[g * kH + j];
    __syncthreads();
    float acc = b[j];
    for (int k = 0; k < kH; k++) acc += ps[k] * W[k * kH + j];
    outv[g * kH + j] = doRelu ? fmaxf(acc, 0.f) : acc;
}

__global__ void k_head3(const float* __restrict__ z, const float* __restrict__ W,
                        const float* __restrict__ b, float* __restrict__ outv) {
    int t = threadIdx.x; // 128 = 64 graphs * 2 classes
    int g = t >> 1, c = t & 1;
    float acc = b[c];
    for (int k = 0; k < kH; k++) acc += z[g * kH + k] * W[k * kC + c];
    outv[g * kC + c] = acc;
}

// ---------------- launch ----------------
extern "C" void kernel_launch(void* const* d_in, const int* in_sizes, int n_in,
                              void* d_out, int out_size, void* d_ws, size_t ws_size,
                              hipStream_t stream) {
    (void)in_sizes; (void)n_in; (void)out_size; (void)ws_size;
    const float* x    = (const float*)d_in[0];
    const int*   src  = (const int*)d_in[1];
    const int*   dst  = (const int*)d_in[2];
    const int*   gid  = (const int*)d_in[3];
    const float* W_in = (const float*)d_in[4];
    const float* b_in = (const float*)d_in[5];
    const float* W1   = (const float*)d_in[6];
    const float* b1   = (const float*)d_in[7];
    const float* W2   = (const float*)d_in[8];
    const float* b2   = (const float*)d_in[9];
    const float* Wm1  = (const float*)d_in[10];
    const float* bm1  = (const float*)d_in[11];
    const float* Wm2  = (const float*)d_in[12];
    const float* bm2  = (const float*)d_in[13];
    const float* Wm3  = (const float*)d_in[14];
    const float* bm3  = (const float*)d_in[15];
    float* out = (float*)d_out;

    char* ws = (char*)d_ws;
    float* h_a     = (float*)(ws + OFF_HA);
    float* h_b     = (float*)(ws + OFF_HB);
    int*   deg_o   = (int*)(ws + OFF_DEGO);
    int*   deg_i   = (int*)(ws + OFF_DEGI);
    int*   cursor  = (int*)(ws + OFF_CUR);
    int*   prefix  = (int*)(ws + OFF_PRE);
    int*   csr_src = (int*)(ws + OFF_CSRS);
    float* csr_cof = (float*)(ws + OFF_CSRC);
    int*   bsums   = (int*)(ws + OFF_BSUM);
    float* pooled  = (float*)(ws + OFF_POOL);
    float* z1      = (float*)(ws + OFF_Z1);
    float* z2      = (float*)(ws + OFF_Z2);

    // zero the three atomic-counter arrays (contiguous) and the pool accumulator
    hipMemsetAsync(ws + OFF_DEGO, 0, 3 * SZ_RN, stream);
    hipMemsetAsync(ws + OFF_POOL, 0, (size_t)kG * kH * 4, stream);

    int egrid = (kR * kE + 255) / 256;
    k_deg<<<egrid, 256, 0, stream>>>(src, dst, deg_o, deg_i);
    k_scan1<<<kR * NBLK, SCAN_TPB, 0, stream>>>(deg_i, prefix, bsums);
    k_scan2<<<1, 128, 0, stream>>>(bsums);
    k_scan3<<<kR * NBLK, SCAN_TPB, 0, stream>>>(prefix, bsums);
    k_fill<<<egrid, 256, 0, stream>>>(src, dst, deg_o, deg_i, prefix, cursor, csr_src, csr_cof);

    k_inlin<<<(kN + 63) / 64, 256, 0, stream>>>(x, W_in, b_in, h_a);

    // layer 1: h_b = relu(sum_r A_r h_a W1_r + sum_r b1_r)
    k_layer<<<kN / 32, 256, 0, stream>>>(h_a, csr_src, csr_cof, prefix, deg_i,
                                         W1, b1, h_b, 1);
    // layer 2: h_a = sum_r A_r h_b W2_r + sum_r b2_r
    k_layer<<<kN / 32, 256, 0, stream>>>(h_b, csr_src, csr_cof, prefix, deg_i,
                                         W2, b2, h_a, 0);

    k_pool_acc<<<(kN + 127) / 128, 128, 0, stream>>>(h_a, gid, pooled);
    k_pool_fin<<<kG, 128, 0, stream>>>(gid, pooled);
    k_head<<<kG, 128, 0, stream>>>(pooled, Wm1, bm1, z1, 1);
    k_head<<<kG, 128, 0, stream>>>(z1, Wm2, bm2, z2, 1);
    k_head3<<<1, 128, 0, stream>>>(z2, Wm3, bm3, out);
}

// Round 4
// 1108.955 us; speedup vs baseline: 1.7394x; 1.3745x over previous
//
#include <hip/hip_runtime.h>

// Problem constants (match reference)
constexpr int kN = 100000;   // nodes
constexpr int kE = 400000;   // edges per relation
constexpr int kR = 4;        // relations
constexpr int kG = 64;       // graphs
constexpr int kIN = 64;      // input feature dim
constexpr int kH = 128;      // hidden dim
constexpr int kC = 2;        // classes

// scan config
constexpr int SCAN_TPB = 256;
constexpr int SCAN_CHUNK = 1024;                      // 4 elements per thread
constexpr int NBLK = (kN + SCAN_CHUNK - 1) / SCAN_CHUNK; // 98 blocks per relation

// ---------------- workspace layout ----------------
constexpr size_t SZ_H  = (size_t)kN * kH * 4;   // 51,200,000
constexpr size_t SZ_RN = (size_t)kR * kN * 4;   // 1,600,000
constexpr size_t SZ_RE = (size_t)kR * kE * 4;   // 6,400,000
constexpr size_t OFF_HA   = 0;
constexpr size_t OFF_HB   = OFF_HA + SZ_H;
constexpr size_t OFF_DEGO = OFF_HB + SZ_H;       // int, zeroed each call
constexpr size_t OFF_DEGI = OFF_DEGO + SZ_RN;    // int, zeroed each call
constexpr size_t OFF_CUR  = OFF_DEGI + SZ_RN;    // int, zeroed each call
constexpr size_t OFF_PRE  = OFF_CUR + SZ_RN;     // int
constexpr size_t OFF_CSRS = OFF_PRE + SZ_RN;     // int  [R*E]
constexpr size_t OFF_CSRC = OFF_CSRS + SZ_RE;    // f32  [R*E]
constexpr size_t OFF_BSUM = OFF_CSRC + SZ_RE;    // int  [R*NBLK]
constexpr size_t OFF_POOL = OFF_BSUM + 4096;     // f32 [G,H], zeroed each call
constexpr size_t OFF_Z1   = OFF_POOL + (size_t)kG * kH * 4;
constexpr size_t OFF_Z2   = OFF_Z1 + (size_t)kG * kH * 4;

// ---------------- CSR build ----------------

__global__ void k_deg(const int* __restrict__ src, const int* __restrict__ dst,
                      int* __restrict__ deg_o, int* __restrict__ deg_i) {
    int i = blockIdx.x * blockDim.x + threadIdx.x;
    if (i >= kR * kE) return;
    int r = i / kE;
    atomicAdd(&deg_o[r * kN + src[i]], 1);
    atomicAdd(&deg_i[r * kN + dst[i]], 1);
}

__global__ void k_scan1(const int* __restrict__ counts, int* __restrict__ prefix,
                        int* __restrict__ bsums) {
    __shared__ int lds[SCAN_TPB];
    int r = blockIdx.x / NBLK;
    int b = blockIdx.x % NBLK;
    int base = b * SCAN_CHUNK;
    int t = threadIdx.x;
    int v[4]; int s = 0;
    #pragma unroll
    for (int k = 0; k < 4; k++) {
        int idx = base + t * 4 + k;
        v[k] = (idx < kN) ? counts[r * kN + idx] : 0;
        s += v[k];
    }
    lds[t] = s; __syncthreads();
    for (int off = 1; off < SCAN_TPB; off <<= 1) {
        int x = (t >= off) ? lds[t - off] : 0;
        __syncthreads();
        lds[t] += x;
        __syncthreads();
    }
    int ex = (t > 0) ? lds[t - 1] : 0;
    int run = ex;
    #pragma unroll
    for (int k = 0; k < 4; k++) {
        int idx = base + t * 4 + k;
        if (idx < kN) prefix[r * kN + idx] = run;
        run += v[k];
    }
    if (t == 0) bsums[blockIdx.x] = lds[SCAN_TPB - 1];
}

__global__ void k_scan2(int* __restrict__ bsums) {
    __shared__ int lds[128];
    int t = threadIdx.x; // 128 threads
    for (int r = 0; r < kR; r++) {
        int v = (t < NBLK) ? bsums[r * NBLK + t] : 0;
        lds[t] = v; __syncthreads();
        for (int off = 1; off < 128; off <<= 1) {
            int x = (t >= off) ? lds[t - off] : 0;
            __syncthreads();
            lds[t] += x;
            __syncthreads();
        }
        int ex = (t > 0) ? lds[t - 1] : 0;
        if (t < NBLK) bsums[r * NBLK + t] = ex;
        __syncthreads();
    }
}

__global__ void k_scan3(int* __restrict__ prefix, const int* __restrict__ bsums) {
    int b = blockIdx.x % NBLK;
    int off = bsums[blockIdx.x];
    int r = blockIdx.x / NBLK;
    int base = b * SCAN_CHUNK + threadIdx.x;
    #pragma unroll
    for (int k = 0; k < 4; k++) {
        int idx = base + k * SCAN_TPB;
        if (idx < kN) prefix[r * kN + idx] += off;
    }
}

__global__ void k_fill(const int* __restrict__ src, const int* __restrict__ dst,
                       const int* __restrict__ deg_o, const int* __restrict__ deg_i,
                       const int* __restrict__ prefix, int* __restrict__ cursor,
                       int* __restrict__ csr_src, float* __restrict__ csr_coef) {
    int i = blockIdx.x * blockDim.x + threadIdx.x;
    if (i >= kR * kE) return;
    int r = i / kE;
    int s = src[i], d = dst[i];
    int pos = prefix[r * kN + d] + atomicAdd(&cursor[r * kN + d], 1);
    float co = rsqrtf((float)max(deg_o[r * kN + s], 1)) *
               rsqrtf((float)max(deg_i[r * kN + d], 1));
    csr_src[r * kE + pos] = s;
    csr_coef[r * kE + pos] = co;
}

// ---------------- input linear ----------------
__global__ __launch_bounds__(256) void k_inlin(const float* __restrict__ x,
                                               const float* __restrict__ W,
                                               const float* __restrict__ b,
                                               float* __restrict__ h) {
    __shared__ float Ws[64][128];
    __shared__ float xs[64][64];
    int t = threadIdx.x;
    int n0 = blockIdx.x * 64;
    for (int i = t; i < 64 * 128; i += 256) Ws[i >> 7][i & 127] = W[i];
    for (int i = t; i < 64 * 64; i += 256) {
        int rr = i >> 6, cc = i & 63;
        int n = n0 + rr;
        xs[rr][cc] = (n < kN) ? x[(size_t)n * kIN + cc] : 0.f;
    }
    __syncthreads();
    int jg = t & 31, j0 = jg * 4, rg = t >> 5; // rg in 0..7, 8 rows each
    float acc[8][4] = {};
    for (int k = 0; k < 64; k++) {
        float4 wv = *(const float4*)&Ws[k][j0];
        #pragma unroll
        for (int i = 0; i < 8; i++) {
            float av = xs[rg * 8 + i][k];
            acc[i][0] += av * wv.x; acc[i][1] += av * wv.y;
            acc[i][2] += av * wv.z; acc[i][3] += av * wv.w;
        }
    }
    #pragma unroll
    for (int i = 0; i < 8; i++) {
        int n = n0 + rg * 8 + i;
        if (n < kN) {
            float4 res;
            res.x = fmaxf(acc[i][0] + b[j0 + 0], 0.f);
            res.y = fmaxf(acc[i][1] + b[j0 + 1], 0.f);
            res.z = fmaxf(acc[i][2] + b[j0 + 2], 0.f);
            res.w = fmaxf(acc[i][3] + b[j0 + 3], 0.f);
            *(float4*)&h[(size_t)n * kH + j0] = res;
        }
    }
}

// ---------------- fused RGCN layer ----------------
// out[n,:] = (relu?)( sum_r (A_r hin)[n,:] @ W_r + sum_r b_r )
// One block = 32 nodes. Per relation: gather-aggregate into LDS As, then FMA
// against W_r read DIRECTLY from global (L1/L2-cached; 512B/wave coalesced).
// LDS = 16 KB only -> high occupancy to hide random-gather latency.
// __launch_bounds__(256, 6): 6 waves/SIMD target = 24 waves/CU.
__global__ __launch_bounds__(256, 6) void k_layer(
    const float* __restrict__ hin, const int* __restrict__ csr_src,
    const float* __restrict__ csr_coef, const int* __restrict__ prefix,
    const int* __restrict__ cnt, const float* __restrict__ W,
    const float* __restrict__ brel, float* __restrict__ out, int doRelu) {
    __shared__ float As[32][128];
    int t = threadIdx.x, wave = t >> 6, lane = t & 63;
    int n0 = blockIdx.x * 32;                 // kN % 32 == 0
    int jg = t & 31, j0 = jg * 4, rg = t >> 5;
    float acc[4][4] = {};
    for (int r = 0; r < kR; r++) {
        __syncthreads();                      // As free (prev relation's reads done)
        // gather phase: wave handles 8 nodes, 2 features per lane
        #pragma unroll
        for (int i = 0; i < 8; i++) {
            int n = n0 + wave * 8 + i;
            int beg = prefix[r * kN + n];
            int c = cnt[r * kN + n];
            const int* sp = csr_src + (size_t)r * kE + beg;
            const float* cp = csr_coef + (size_t)r * kE + beg;
            float a0 = 0.f, a1 = 0.f;
            for (int e = 0; e < c; e++) {
                int s = sp[e];
                float co = cp[e];
                const float* hr = hin + (size_t)s * kH;
                a0 += co * hr[lane];
                a1 += co * hr[64 + lane];
            }
            As[wave * 8 + i][lane] = a0;
            As[wave * 8 + i][64 + lane] = a1;
        }
        __syncthreads();                      // As ready
        const float* Wr = W + (size_t)r * kH * kH;
        for (int k = 0; k < kH; k++) {
            float4 wv = *(const float4*)&Wr[(size_t)k * kH + j0];
            #pragma unroll
            for (int i = 0; i < 4; i++) {
                float av = As[rg * 4 + i][k];
                acc[i][0] += av * wv.x; acc[i][1] += av * wv.y;
                acc[i][2] += av * wv.z; acc[i][3] += av * wv.w;
            }
        }
    }
    float4 bias;
    bias.x = brel[0 * kH + j0 + 0] + brel[1 * kH + j0 + 0] + brel[2 * kH + j0 + 0] + brel[3 * kH + j0 + 0];
    bias.y = brel[0 * kH + j0 + 1] + brel[1 * kH + j0 + 1] + brel[2 * kH + j0 + 1] + brel[3 * kH + j0 + 1];
    bias.z = brel[0 * kH + j0 + 2] + brel[1 * kH + j0 + 2] + brel[2 * kH + j0 + 2] + brel[3 * kH + j0 + 2];
    bias.w = brel[0 * kH + j0 + 3] + brel[1 * kH + j0 + 3] + brel[2 * kH + j0 + 3] + brel[3 * kH + j0 + 3];
    #pragma unroll
    for (int i = 0; i < 4; i++) {
        int n = n0 + rg * 4 + i;
        float4 res;
        res.x = bias.x + acc[i][0]; res.y = bias.y + acc[i][1];
        res.z = bias.z + acc[i][2]; res.w = bias.w + acc[i][3];
        if (doRelu) {
            res.x = fmaxf(res.x, 0.f); res.y = fmaxf(res.y, 0.f);
            res.z = fmaxf(res.z, 0.f); res.w = fmaxf(res.w, 0.f);
        }
        *(float4*)&out[(size_t)n * kH + j0] = res;
    }
}

// ---------------- pooling (2-stage) ----------------
__global__ void k_pool_acc(const float* __restrict__ h, const int* __restrict__ gid,
                           float* __restrict__ pooled) {
    int j = threadIdx.x;                 // 128 threads = feature
    int base = blockIdx.x * 128;
    if (base >= kN) return;
    int end = min(base + 128, kN);
    int curg = gid[base];
    float acc = 0.f;
    for (int n = base; n < end; n++) {
        int g = gid[n];                  // uniform -> scalar load
        if (g != curg) {
            atomicAdd(&pooled[curg * kH + j], acc);
            acc = 0.f; curg = g;
        }
        acc += h[(size_t)n * kH + j];
    }
    atomicAdd(&pooled[curg * kH + j], acc);
}

__global__ void k_pool_fin(const int* __restrict__ gid, float* __restrict__ pooled) {
    int g = blockIdx.x, j = threadIdx.x; // 64 blocks x 128 threads
    int lo = 0, hi = kN;
    while (lo < hi) { int m = (lo + hi) >> 1; if (gid[m] < g) lo = m + 1; else hi = m; }
    int s = lo;
    lo = s; hi = kN;
    while (lo < hi) { int m = (lo + hi) >> 1; if (gid[m] <= g) lo = m + 1; else hi = m; }
    int c = lo - s;
    pooled[g * kH + j] /= (float)max(c, 1);
}

// ---------------- MLP head ----------------
__global__ void k_head(const float* __restrict__ in, const float* __restrict__ W,
                       const float* __restrict__ b, float* __restrict__ outv, int doRelu) {
    __shared__ float ps[128];
    int g = blockIdx.x, j = threadIdx.x;
    ps[j] = in[g * kH + j];
    __syncthreads();
    float acc = b[j];
    for (int k = 0; k < kH; k++) acc += ps[k] * W[k * kH + j];
    outv[g * kH + j] = doRelu ? fmaxf(acc, 0.f) : acc;
}

__global__ void k_head3(const float* __restrict__ z, const float* __restrict__ W,
                        const float* __restrict__ b, float* __restrict__ outv) {
    int t = threadIdx.x; // 128 = 64 graphs * 2 classes
    int g = t >> 1, c = t & 1;
    float acc = b[c];
    for (int k = 0; k < kH; k++) acc += z[g * kH + k] * W[k * kC + c];
    outv[g * kC + c] = acc;
}

// ---------------- launch ----------------
extern "C" void kernel_launch(void* const* d_in, const int* in_sizes, int n_in,
                              void* d_out, int out_size, void* d_ws, size_t ws_size,
                              hipStream_t stream) {
    (void)in_sizes; (void)n_in; (void)out_size; (void)ws_size;
    const float* x    = (const float*)d_in[0];
    const int*   src  = (const int*)d_in[1];
    const int*   dst  = (const int*)d_in[2];
    const int*   gid  = (const int*)d_in[3];
    const float* W_in = (const float*)d_in[4];
    const float* b_in = (const float*)d_in[5];
    const float* W1   = (const float*)d_in[6];
    const float* b1   = (const float*)d_in[7];
    const float* W2   = (const float*)d_in[8];
    const float* b2   = (const float*)d_in[9];
    const float* Wm1  = (const float*)d_in[10];
    const float* bm1  = (const float*)d_in[11];
    const float* Wm2  = (const float*)d_in[12];
    const float* bm2  = (const float*)d_in[13];
    const float* Wm3  = (const float*)d_in[14];
    const float* bm3  = (const float*)d_in[15];
    float* out = (float*)d_out;

    char* ws = (char*)d_ws;
    float* h_a     = (float*)(ws + OFF_HA);
    float* h_b     = (float*)(ws + OFF_HB);
    int*   deg_o   = (int*)(ws + OFF_DEGO);
    int*   deg_i   = (int*)(ws + OFF_DEGI);
    int*   cursor  = (int*)(ws + OFF_CUR);
    int*   prefix  = (int*)(ws + OFF_PRE);
    int*   csr_src = (int*)(ws + OFF_CSRS);
    float* csr_cof = (float*)(ws + OFF_CSRC);
    int*   bsums   = (int*)(ws + OFF_BSUM);
    float* pooled  = (float*)(ws + OFF_POOL);
    float* z1      = (float*)(ws + OFF_Z1);
    float* z2      = (float*)(ws + OFF_Z2);

    // zero the three atomic-counter arrays (contiguous) and the pool accumulator
    hipMemsetAsync(ws + OFF_DEGO, 0, 3 * SZ_RN, stream);
    hipMemsetAsync(ws + OFF_POOL, 0, (size_t)kG * kH * 4, stream);

    int egrid = (kR * kE + 255) / 256;
    k_deg<<<egrid, 256, 0, stream>>>(src, dst, deg_o, deg_i);
    k_scan1<<<kR * NBLK, SCAN_TPB, 0, stream>>>(deg_i, prefix, bsums);
    k_scan2<<<1, 128, 0, stream>>>(bsums);
    k_scan3<<<kR * NBLK, SCAN_TPB, 0, stream>>>(prefix, bsums);
    k_fill<<<egrid, 256, 0, stream>>>(src, dst, deg_o, deg_i, prefix, cursor, csr_src, csr_cof);

    k_inlin<<<(kN + 63) / 64, 256, 0, stream>>>(x, W_in, b_in, h_a);

    // layer 1: h_b = relu(sum_r A_r h_a W1_r + sum_r b1_r)
    k_layer<<<kN / 32, 256, 0, stream>>>(h_a, csr_src, csr_cof, prefix, deg_i,
                                         W1, b1, h_b, 1);
    // layer 2: h_a = sum_r A_r h_b W2_r + sum_r b2_r
    k_layer<<<kN / 32, 256, 0, stream>>>(h_b, csr_src, csr_cof, prefix, deg_i,
                                         W2, b2, h_a, 0);

    k_pool_acc<<<(kN + 127) / 128, 128, 0, stream>>>(h_a, gid, pooled);
    k_pool_fin<<<kG, 128, 0, stream>>>(gid, pooled);
    k_head<<<kG, 128, 0, stream>>>(pooled, Wm1, bm1, z1, 1);
    k_head<<<kG, 128, 0, stream>>>(z1, Wm2, bm2, z2, 1);
    k_head3<<<1, 128, 0, stream>>>(z2, Wm3, bm3, out);
}